// Round 9
// baseline (1879.177 us; speedup 1.0000x reference)
//
#include <hip/hip_runtime.h>
#include <hip/hip_bf16.h>
#include <math.h>

#define Bb 64
#define Tt 1024
#define Dd 128
#define Hh 256
#define G4 1024  // 4*H
#define Vv 128
#define NVh 3
#define BT (Bb*Tt)

typedef __fp16 half2_t __attribute__((ext_vector_type(2)));
typedef __fp16 f16x4 __attribute__((ext_vector_type(4)));
typedef __fp16 f16x8 __attribute__((ext_vector_type(8)));
typedef float f32x4 __attribute__((ext_vector_type(4)));

__device__ __forceinline__ half2_t pkh(float a, float b) {
    return __builtin_amdgcn_cvt_pkrtz(a, b);
}
__device__ __forceinline__ float fdot2(half2_t a, half2_t b, float c) {
#if __has_builtin(__builtin_amdgcn_fdot2)
    return __builtin_amdgcn_fdot2(a, b, c, false);
#else
    return c + (float)a[0] * (float)b[0] + (float)a[1] * (float)b[1];
#endif
}
__device__ __forceinline__ half2_t bch(unsigned int x) {
    return __builtin_bit_cast(half2_t, x);
}
__device__ __forceinline__ float fsig(float x) {
    return __builtin_amdgcn_rcpf(1.f + __expf(-x));
}
__device__ __forceinline__ float ftanh(float x) {
    float e = __expf(-2.f * fabsf(x));
    float r = (1.f - e) * __builtin_amdgcn_rcpf(1.f + e);
    return copysignf(r, x);
}

// ---------------- Kernel 0: f32 -> f16 convert (RNE), n multiple of 4 ----------
__global__ __launch_bounds__(256) void cvt16(const float* __restrict__ in,
                                             __fp16* __restrict__ out, int n4) {
    int i = blockIdx.x * 256 + threadIdx.x;
    if (i < n4) {
        float4 v = ((const float4*)in)[i];
        f16x4 o;
        o[0] = (__fp16)v.x; o[1] = (__fp16)v.y;
        o[2] = (__fp16)v.z; o[3] = (__fp16)v.w;
        ((f16x4*)out)[i] = o;
    }
}

// ---------------- Kernel A: gx via MFMA f16 -------------------------------------
__global__ __launch_bounds__(256) void gx_mfma(const __fp16* __restrict__ x16,
                                               const __fp16* __restrict__ Wih16,
                                               const float* __restrict__ bih,
                                               const float* __restrict__ bhh,
                                               __fp16* __restrict__ gx2) {
    const int tid = threadIdx.x;
    const int w = tid >> 6, l = tid & 63;
    const int mb = blockIdx.x * 64 + w * 16;
    const int jj0 = blockIdx.y * 16;
    const int lr = l & 15, lk = l >> 4;

    f32x4 acc[4] = {};
    const __fp16* xa = x16 + (size_t)(mb + lr) * Dd + lk * 8;
    #pragma unroll
    for (int ks = 0; ks < 4; ++ks) {                 // K=128, 32 per step
        f16x8 af = *(const f16x8*)(xa + ks * 32);
        #pragma unroll
        for (int g = 0; g < 4; ++g) {
            const __fp16* bb = Wih16 + (size_t)(g * 256 + jj0 + lr) * Dd + ks * 32 + lk * 8;
            f16x8 bf = *(const f16x8*)bb;
            acc[g] = __builtin_amdgcn_mfma_f32_16x16x32_f16(af, bf, acc[g], 0, 0, 0);
        }
    }
    float bsum[4];
    #pragma unroll
    for (int g = 0; g < 4; ++g) {
        int j = g * 256 + jj0 + lr;
        bsum[g] = bih[j] + bhh[j];
    }
    #pragma unroll
    for (int r = 0; r < 4; ++r) {
        int m = mb + lk * 4 + r;                     // D row = (lane>>4)*4+reg
        f16x4 o;
        o[0] = (__fp16)(acc[0][r] + bsum[0]);
        o[1] = (__fp16)(acc[1][r] + bsum[1]);
        o[2] = (__fp16)(acc[2][r] + bsum[2]);
        o[3] = (__fp16)(acc[3][r] + bsum[3]);
        *(f16x4*)&gx2[((size_t)m * Hh + jj0 + lr) * 4] = o;
    }
}

// ---------------- Kernel B: persistent LSTM scan (v8: S=4 K-split) --------------
// 64 blocks x 512 threads, launch_bounds(512,1) -> 256 arch VGPRs, 1 block/CU.
// Thread (jj=tid&127, s=tid>>7) owns all 4 gate rows of h-indices {jj, jj+128},
// K-quarter [s*64, s*64+64) (32 pairs per row, 256 pairs total):
//   gates i,f,g (6 rows)        : w[6][32]  = 192 pairs in regs
//   gate  o: pairs [0,8) /row   : wo[2][8]  =  16 pairs in regs   (208 total)
//   gate  o: pairs [8,32)/row   : 96KB LDS, 12 b128/thread (conflict-free)
// h-read: 8 b128/thread (K-quarter). Partials exchanged via pex (16KB);
// s=0 finishes h[jj], s=1 finishes h[jj+128] (parallel epilogue); s=2,3 write-only.
__global__ __launch_bounds__(512, 1) void lstm_scan(const __fp16* __restrict__ gx2,
                                                    const float* __restrict__ Whh,
                                                    __fp16* __restrict__ hs16) {
    __shared__ __align__(16) uint4 wlds[12 * 512];   // 96KB
    __shared__ __align__(16) float4 pex[4 * 2 * 128];// 16KB: [s][jjp][jj]
    __shared__ __align__(16) __fp16 hsh[Hh];         // 512B
    const int tid = threadIdx.x;
    const int jj = tid & 127;
    const int s = tid >> 7;            // wave-uniform (2 waves per s)
    const int b = blockIdx.x;

    // ---- stage W: rows = gate g x jjp in {jj, jj+128}, K-slice [s*64,s*64+64) ----
    half2_t w[6][32];                  // gates i,f,g
    half2_t wo[2][8];                  // gate o, pairs 0..7
    #pragma unroll
    for (int g = 0; g < 3; ++g) {
        #pragma unroll
        for (int p = 0; p < 2; ++p) {
            const float* wr = Whh + (size_t)(g * 256 + p * 128 + jj) * Hh + s * 64;
            #pragma unroll
            for (int c = 0; c < 8; ++c) {
                float4 f0 = *(const float4*)&wr[c * 8];
                float4 f1 = *(const float4*)&wr[c * 8 + 4];
                w[g*2+p][c*4+0] = pkh(f0.x, f0.y);
                w[g*2+p][c*4+1] = pkh(f0.z, f0.w);
                w[g*2+p][c*4+2] = pkh(f1.x, f1.y);
                w[g*2+p][c*4+3] = pkh(f1.z, f1.w);
            }
        }
    }
    #pragma unroll
    for (int p = 0; p < 2; ++p) {
        const float* wr = Whh + (size_t)(3 * 256 + p * 128 + jj) * Hh + s * 64;
        #pragma unroll
        for (int c = 0; c < 2; ++c) {          // pairs 0..7 -> regs
            float4 f0 = *(const float4*)&wr[c * 8];
            float4 f1 = *(const float4*)&wr[c * 8 + 4];
            wo[p][c*4+0] = pkh(f0.x, f0.y);
            wo[p][c*4+1] = pkh(f0.z, f0.w);
            wo[p][c*4+2] = pkh(f1.x, f1.y);
            wo[p][c*4+3] = pkh(f1.z, f1.w);
        }
        #pragma unroll
        for (int c = 2; c < 8; ++c) {          // pairs 8..31 -> LDS
            float4 f0 = *(const float4*)&wr[c * 8];
            float4 f1 = *(const float4*)&wr[c * 8 + 4];
            uint4 o;
            o.x = __builtin_bit_cast(unsigned int, pkh(f0.x, f0.y));
            o.y = __builtin_bit_cast(unsigned int, pkh(f0.z, f0.w));
            o.z = __builtin_bit_cast(unsigned int, pkh(f1.x, f1.y));
            o.w = __builtin_bit_cast(unsigned int, pkh(f1.z, f1.w));
            wlds[((c - 2) * 2 + p) * 512 + tid] = o;
        }
    }
    if (tid < 128) ((unsigned int*)hsh)[tid] = 0u;
    float c_state = 0.f;
    __syncthreads();

    // s<2 threads finish h for index hj = jj + s*128
    const int hj = jj + (s & 1) * 128;
    const __fp16* gxb = gx2 + ((size_t)b * Tt * Hh + hj) * 4;  // step stride 1024 f16
    __fp16* hsb = hs16 + (size_t)b * Tt * Hh + hj;

    float g0 = 0.f, g1 = 0.f, g2 = 0.f, g3 = 0.f;
    if (s < 2) {
        uint2 gv = *(const uint2*)gxb;
        half2_t pp = bch(gv.x), qq = bch(gv.y);
        g0 = (float)pp[0]; g1 = (float)pp[1]; g2 = (float)qq[0]; g3 = (float)qq[1];
    }

    const uint4* h4 = (const uint4*)hsh + (s << 3);  // 8 uint4 per K-quarter
    __fp16 hprev = (__fp16)0.f;

    for (int t = 0; t < Tt; ++t) {
        // deferred h store from step t-1 (keeps vmcnt drain off barrier-2)
        if (s < 2 && t > 0) hsb[(size_t)(t - 1) * Hh] = hprev;

        // prefetch next step's gx (independent of h)
        float n0 = 0.f, n1 = 0.f, n2 = 0.f, n3 = 0.f;
        if (s < 2) {
            const __fp16* gn = gxb + (size_t)(t + 1 < Tt ? t + 1 : t) * 1024;
            uint2 gv = *(const uint2*)gn;
            half2_t pp = bch(gv.x), qq = bch(gv.y);
            n0 = (float)pp[0]; n1 = (float)pp[1]; n2 = (float)qq[0]; n3 = (float)qq[1];
        }

        float ai0 = 0.f, ai1 = 0.f, af0 = 0.f, af1 = 0.f;
        float ag0 = 0.f, ag1 = 0.f, ao0 = 0.f, ao1 = 0.f;

        #pragma unroll
        for (int c = 0; c < 8; ++c) {
            uint4 hv = h4[c];                     // uniform broadcast read
            half2_t u0 = bch(hv.x), u1 = bch(hv.y);
            half2_t u2 = bch(hv.z), u3 = bch(hv.w);
            ai0 = fdot2(w[0][c*4+0], u0, ai0); ai1 = fdot2(w[1][c*4+0], u0, ai1);
            af0 = fdot2(w[2][c*4+0], u0, af0); af1 = fdot2(w[3][c*4+0], u0, af1);
            ag0 = fdot2(w[4][c*4+0], u0, ag0); ag1 = fdot2(w[5][c*4+0], u0, ag1);
            ai0 = fdot2(w[0][c*4+1], u1, ai0); ai1 = fdot2(w[1][c*4+1], u1, ai1);
            af0 = fdot2(w[2][c*4+1], u1, af0); af1 = fdot2(w[3][c*4+1], u1, af1);
            ag0 = fdot2(w[4][c*4+1], u1, ag0); ag1 = fdot2(w[5][c*4+1], u1, ag1);
            ai0 = fdot2(w[0][c*4+2], u2, ai0); ai1 = fdot2(w[1][c*4+2], u2, ai1);
            af0 = fdot2(w[2][c*4+2], u2, af0); af1 = fdot2(w[3][c*4+2], u2, af1);
            ag0 = fdot2(w[4][c*4+2], u2, ag0); ag1 = fdot2(w[5][c*4+2], u2, ag1);
            ai0 = fdot2(w[0][c*4+3], u3, ai0); ai1 = fdot2(w[1][c*4+3], u3, ai1);
            af0 = fdot2(w[2][c*4+3], u3, af0); af1 = fdot2(w[3][c*4+3], u3, af1);
            ag0 = fdot2(w[4][c*4+3], u3, ag0); ag1 = fdot2(w[5][c*4+3], u3, ag1);
            if (c < 2) {
                ao0 = fdot2(wo[0][c*4+0], u0, ao0); ao1 = fdot2(wo[1][c*4+0], u0, ao1);
                ao0 = fdot2(wo[0][c*4+1], u1, ao0); ao1 = fdot2(wo[1][c*4+1], u1, ao1);
                ao0 = fdot2(wo[0][c*4+2], u2, ao0); ao1 = fdot2(wo[1][c*4+2], u2, ao1);
                ao0 = fdot2(wo[0][c*4+3], u3, ao0); ao1 = fdot2(wo[1][c*4+3], u3, ao1);
            } else {
                uint4 w0v = wlds[((c - 2) * 2 + 0) * 512 + tid];
                uint4 w1v = wlds[((c - 2) * 2 + 1) * 512 + tid];
                ao0 = fdot2(bch(w0v.x), u0, ao0); ao1 = fdot2(bch(w1v.x), u0, ao1);
                ao0 = fdot2(bch(w0v.y), u1, ao0); ao1 = fdot2(bch(w1v.y), u1, ao1);
                ao0 = fdot2(bch(w0v.z), u2, ao0); ao1 = fdot2(bch(w1v.z), u2, ao1);
                ao0 = fdot2(bch(w0v.w), u3, ao0); ao1 = fdot2(bch(w1v.w), u3, ao1);
            }
        }

        // publish partials: [s][jjp][jj], gates packed (i,f,g,o)
        pex[(s * 2 + 0) * 128 + jj] = make_float4(ai0, af0, ag0, ao0);
        pex[(s * 2 + 1) * 128 + jj] = make_float4(ai1, af1, ag1, ao1);
        __syncthreads();                 // pex visible; all hsh reads complete

        if (s < 2) {
            const int p = s;             // jjp this thread finishes
            float own0 = (p == 0) ? ai0 : ai1;
            float own1 = (p == 0) ? af0 : af1;
            float own2 = (p == 0) ? ag0 : ag1;
            float own3 = (p == 0) ? ao0 : ao1;
            float4 q1 = pex[(((s + 1) & 3) * 2 + p) * 128 + jj];
            float4 q2 = pex[(((s + 2) & 3) * 2 + p) * 128 + jj];
            float4 q3 = pex[(((s + 3) & 3) * 2 + p) * 128 + jj];
            float A0 = own0 + q1.x + q2.x + q3.x + g0;
            float A1 = own1 + q1.y + q2.y + q3.y + g1;
            float A2 = own2 + q1.z + q2.z + q3.z + g2;
            float A3 = own3 + q1.w + q2.w + q3.w + g3;
            float si = fsig(A0);
            float sf = fsig(A1);
            float tg = ftanh(A2);
            float so = fsig(A3);
            c_state = sf * c_state + si * tg;
            float hn = so * ftanh(c_state);
            hprev = (__fp16)hn;
            hsh[hj] = hprev;
        }
        g0 = n0; g1 = n1; g2 = n2; g3 = n3;
        __syncthreads();                 // h(t) visible for step t+1
    }
    if (s < 2) hsb[(size_t)(Tt - 1) * Hh] = hprev;
}

// ---------------- Kernel C: head via MFMA f16 -----------------------------------
__global__ __launch_bounds__(256) void head_mfma(const __fp16* __restrict__ hs16,
                                                 const __fp16* __restrict__ hw16,
                                                 const float* __restrict__ hb,
                                                 float* __restrict__ out) {
    const int tid = threadIdx.x;
    const int w = tid >> 6, l = tid & 63;
    const int mb = blockIdx.x * 64 + w * 16;
    const int n0 = blockIdx.y * 64;                  // 4 N-tiles of 16
    const int lr = l & 15, lk = l >> 4;

    f32x4 acc[4] = {};
    const __fp16* aa = hs16 + (size_t)(mb + lr) * Hh + lk * 8;
    #pragma unroll
    for (int ks = 0; ks < 8; ++ks) {                 // K=256, 32 per step
        f16x8 af = *(const f16x8*)(aa + ks * 32);
        #pragma unroll
        for (int nt = 0; nt < 4; ++nt) {
            const __fp16* bb = hw16 + (size_t)(n0 + nt * 16 + lr) * Hh + ks * 32 + lk * 8;
            f16x8 bf = *(const f16x8*)bb;
            acc[nt] = __builtin_amdgcn_mfma_f32_16x16x32_f16(af, bf, acc[nt], 0, 0, 0);
        }
    }
    #pragma unroll
    for (int nt = 0; nt < 4; ++nt) {
        int nv = n0 + nt * 16 + lr;
        int nh = nv >> 7, v = nv & 127;
        float bv = hb[nv];
        #pragma unroll
        for (int r = 0; r < 4; ++r) {
            int m = mb + lk * 4 + r;
            out[(size_t)nh * BT * Vv + (size_t)m * Vv + v] = acc[nt][r] + bv;
        }
    }
}

extern "C" void kernel_launch(void* const* d_in, const int* in_sizes, int n_in,
                              void* d_out, int out_size, void* d_ws, size_t ws_size,
                              hipStream_t stream) {
    const float* x    = (const float*)d_in[0];
    const float* Wih  = (const float*)d_in[1];
    const float* Whh  = (const float*)d_in[2];
    const float* bih  = (const float*)d_in[3];
    const float* bhh  = (const float*)d_in[4];
    const float* hw   = (const float*)d_in[5];
    const float* hb   = (const float*)d_in[6];
    float* out = (float*)d_out;

    // workspace carve (f16): x16 | Wih16 | hw16 | gx2 | hs16  (~176 MB total)
    __fp16* x16   = (__fp16*)d_ws;                     // BT*128
    __fp16* Wih16 = x16 + (size_t)BT * Dd;             // 1024*128
    __fp16* hw16  = Wih16 + (size_t)G4 * Dd;           // 384*256
    __fp16* gx2   = hw16 + (size_t)NVh * Vv * Hh;      // BT*1024 (packed f16x4)
    __fp16* hs16  = gx2 + (size_t)BT * G4;             // BT*256

    cvt16<<<(BT * Dd / 4 + 255) / 256, 256, 0, stream>>>(x, x16, BT * Dd / 4);
    cvt16<<<(G4 * Dd / 4 + 255) / 256, 256, 0, stream>>>(Wih, Wih16, G4 * Dd / 4);
    cvt16<<<(NVh * Vv * Hh / 4 + 255) / 256, 256, 0, stream>>>(hw, hw16, NVh * Vv * Hh / 4);

    gx_mfma<<<dim3(BT / 64, Hh / 16), 256, 0, stream>>>(x16, Wih16, bih, bhh, gx2);
    lstm_scan<<<Bb, 512, 0, stream>>>(gx2, Whh, hs16);
    head_mfma<<<dim3(BT / 64, (NVh * Vv) / 64), 256, 0, stream>>>(hs16, hw16, hb, out);
}